// Round 2
// 236.436 us; speedup vs baseline: 1.0297x; 1.0297x over previous
//
#include <hip/hip_runtime.h>

// Triplet loss: mean(relu(|(a-p)W|^2 - |(a-n)W|^2 + 0.2)); bias cancels.
//
// R4 = R3 with hardened waitcnt bookkeeping (R3's bench died at container
// level; vmcnt(14) relied on the compiler placing the 8 W-loads between
// the two STAGEs — vmcnt(6) is placement-independent).
//
// Design (from R3): R2 was latency-bound with MLP~1 (VGPR_Count=64 under
// launch_bounds(512,4); ~14 serialized loads/iter -> 1.28 TB/s, all pipes
// idle). R4 stages each wave's A/P/N chunk into its OWN 2x6KB LDS
// double-buffer via global_load_lds (no VGPRs held by in-flight data),
// counted s_waitcnt vmcnt(6) (never 0 in-loop) so chunk c+1 streams under
// chunk c's compute. No barriers in the main loop -> 8 independent wave
// pipelines per CU. Global source addresses are pre-arranged so LDS holds
// data in exact MFMA fragment order: ds_read_b128 at lane*16B
// (conflict-free). Pack u,v via v_cvt_pk_bf16_f32 (RNE, same as f2bf).
// LDS 96KB (1 block/CU), reduce tree (unchanged from R2) aliased on top.
//
// Layout (gfx950, mfma_f32_16x16x32_bf16):
//   A: lane holds A[m=lane&15][k=(lane>>4)*8+j]  (8 bf16)
//   B: lane holds B[k=(lane>>4)*8+j][n=lane&15]
//   C/D: lane holds D[row=(lane>>4)*4+reg][col=lane&15]

#define KDIM  2304   // 48*48
#define EMBD  128
#define BATCH 8192
#define NT    8      // 128 / 16 n-tiles
#define NW    8      // waves per block
#define CPW   9      // K-chunks (of 32) per wave: 72/8
#define ALPHA 0.2f

typedef __attribute__((ext_vector_type(8))) short short8;
typedef __attribute__((ext_vector_type(4))) float f32x4;
typedef __attribute__((ext_vector_type(4))) unsigned int u32x4;

#define AS1 __attribute__((address_space(1)))
#define AS3 __attribute__((address_space(3)))

__device__ __forceinline__ unsigned short f2bf(float f) {
    unsigned u = __builtin_bit_cast(unsigned, f);
    u += 0x7FFFu + ((u >> 16) & 1u);       // round-to-nearest-even
    return (unsigned short)(u >> 16);
}

// Coalesced-read pack: Wp[((c*8+t)*64+l)*8+j] = bf16(W[k][n]),
// k = c*32 + (l>>4)*8 + j, n = t*16 + (l&15).   (unchanged from R2)
__global__ void pack_w_kernel(const float* __restrict__ W,
                              unsigned short* __restrict__ Wp) {
    int tid = blockIdx.x * blockDim.x + threadIdx.x;   // 0 .. 2304*128-1
    int n = tid & 127;
    int k = tid >> 7;
    int c = k >> 5;
    int q = (k >> 3) & 3;
    int j = k & 7;
    int t = n >> 4;
    int l = q * 16 + (n & 15);
    Wp[(size_t)(((c * 8 + t) * 64) + l) * 8 + j] = f2bf(W[tid]);
}

__device__ __forceinline__ unsigned cvtpk(float lo, float hi) {
    unsigned r;
    asm("v_cvt_pk_bf16_f32 %0, %1, %2" : "=v"(r) : "v"(lo), "v"(hi));
    return r;
}

// 16B/lane global->LDS DMA: LDS dest = uniform base + lane*16,
// global src is per-lane (pre-swizzled into fragment order).
__device__ __forceinline__ void gll16(const float* g, char* l) {
    __builtin_amdgcn_global_load_lds((AS1 void*)(void*)g, (AS3 void*)l, 16, 0, 0);
}

// 6 fragment reads (a_lo,a_hi,p_lo,p_hi,n_lo,n_hi) from this wave's
// buffer. lgkmcnt(0) inside the asm block => outputs valid at block end
// (no rule-18 hoist hazard: MFMA consumes asm outputs, data-dependent).
// "memory" clobber keeps the next iteration's global_load_lds from
// hoisting above these reads (buffer reuse at c+2).
__device__ __forceinline__ void lds_read6(const char* p, f32x4& a0, f32x4& a1,
                                          f32x4& p0, f32x4& p1,
                                          f32x4& n0, f32x4& n1) {
    const AS3 char* lp = (const AS3 char*)p;
    asm volatile(
        "ds_read_b128 %0, %6 offset:0\n\t"
        "ds_read_b128 %1, %6 offset:1024\n\t"
        "ds_read_b128 %2, %6 offset:2048\n\t"
        "ds_read_b128 %3, %6 offset:3072\n\t"
        "ds_read_b128 %4, %6 offset:4096\n\t"
        "ds_read_b128 %5, %6 offset:5120\n\t"
        "s_waitcnt lgkmcnt(0)"
        : "=&v"(a0), "=&v"(a1), "=&v"(p0), "=&v"(p1), "=&v"(n0), "=&v"(n1)
        : "v"(lp)
        : "memory");
}

__global__ __launch_bounds__(512, 2) void triplet_kernel(
    const float* __restrict__ A, const float* __restrict__ P,
    const float* __restrict__ Ng, const unsigned short* __restrict__ Wp,
    float* __restrict__ out)
{
    // 8 waves x (2 bufs x 6KB) staging; reduce tree (64KB) aliased after.
    __shared__ __align__(16) char smem[NW * 12288];

    const int lane = threadIdx.x & 63;
    const int wave = threadIdx.x >> 6;
    const int c0   = wave * CPW;             // this wave's first K-chunk

    // Per-lane global base in fragment order: row = blk*16 + (lane&15),
    // col = (lane>>4)*8 floats; c0 folded in.
    const size_t goff = (size_t)(blockIdx.x * 16 + (lane & 15)) * KDIM
                      + (size_t)(lane >> 4) * 8 + (size_t)c0 * 32;
    const float* gA = A  + goff;
    const float* gP = P  + goff;
    const float* gN = Ng + goff;

    char* wb = smem + wave * 12288;          // wave-private staging

    const short8* wp = (const short8*)Wp + lane + (size_t)c0 * NT * 64;

    f32x4 aU[NT], aV[NT];
#pragma unroll
    for (int t = 0; t < NT; ++t) {
        aU[t] = (f32x4){0.f, 0.f, 0.f, 0.f};
        aV[t] = (f32x4){0.f, 0.f, 0.f, 0.f};
    }

    // buf layout (6KB): A_j03 @0, A_j47 @1024, P @2048/3072, N @4096/5120
#define STAGE(cc, bufoff)                                   \
    do {                                                    \
        const float* _a = gA + (cc) * 32;                   \
        const float* _p = gP + (cc) * 32;                   \
        const float* _n = gN + (cc) * 32;                   \
        char* _b = wb + (bufoff);                           \
        gll16(_a,     _b);                                  \
        gll16(_a + 4, _b + 1024);                           \
        gll16(_p,     _b + 2048);                           \
        gll16(_p + 4, _b + 3072);                           \
        gll16(_n,     _b + 4096);                           \
        gll16(_n + 4, _b + 5120);                           \
    } while (0)

    STAGE(0, 0);                             // prologue: chunk 0 -> buf0

    const char* rp0 = wb + lane * 16;
    const char* rp1 = wb + 6144 + lane * 16;

#pragma unroll
    for (int c = 0; c < CPW; ++c) {
        // 1. W fragments for chunk c (coalesced 1KB, L2-resident).
        //    Issued early: a full compute-phase of slack before the MFMA.
        short8 wf[NT];
#pragma unroll
        for (int t = 0; t < NT; ++t) wf[t] = wp[c * 512 + t * 64];

        // 2. prefetch chunk c+1 into the other buffer, then counted wait.
        //    The ONLY vmem ops guaranteed younger than stage(c) are
        //    stage(c+1)'s 6 (asm memory fences pin the order), so
        //    vmcnt(6) retires stage(c) regardless of where the compiler
        //    placed the W loads, and never drains the prefetch.
        if (c + 1 < CPW) {
            STAGE(c + 1, ((c + 1) & 1) * 6144);
            asm volatile("s_waitcnt vmcnt(6)" ::: "memory");
        } else {
            asm volatile("s_waitcnt vmcnt(0)" ::: "memory");  // tail, once
        }

        // 3. fragment reads (conflict-free: lane-contiguous 16B)
        f32x4 xa0, xa1, xp0, xp1, xn0, xn1;
        lds_read6((c & 1) ? rp1 : rp0, xa0, xa1, xp0, xp1, xn0, xn1);

        // 4. u = a-p, v = a-n; pack to bf16 via v_cvt_pk (RNE)
        f32x4 ul = xa0 - xp0, uh = xa1 - xp1;
        f32x4 vl = xa0 - xn0, vh = xa1 - xn1;
        u32x4 uw, vw;
        uw[0] = cvtpk(ul[0], ul[1]); uw[1] = cvtpk(ul[2], ul[3]);
        uw[2] = cvtpk(uh[0], uh[1]); uw[3] = cvtpk(uh[2], uh[3]);
        vw[0] = cvtpk(vl[0], vl[1]); vw[1] = cvtpk(vl[2], vl[3]);
        vw[2] = cvtpk(vh[0], vh[1]); vw[3] = cvtpk(vh[2], vh[3]);
        short8 uf = __builtin_bit_cast(short8, uw);
        short8 vf = __builtin_bit_cast(short8, vw);

        // 5. MFMA (compiler inserts its own counted wait for wf)
#pragma unroll
        for (int t = 0; t < NT; ++t) {
            aU[t] = __builtin_amdgcn_mfma_f32_16x16x32_bf16(uf, wf[t], aU[t], 0, 0, 0);
            aV[t] = __builtin_amdgcn_mfma_f32_16x16x32_bf16(vf, wf[t], aV[t], 0, 0, 0);
        }
    }

    __syncthreads();

    // ---- cross-wave fragment reduce: 8 -> 4 -> 2 -> 1 (wave 0 holds sum),
    //      aliased onto the staging LDS (64KB of the 96KB) ----
    float (*lds)[2][NT][64][4] = (float(*)[2][NT][64][4])(void*)smem;

#define STORE_FRAGS(r)                                              \
    do {                                                            \
        _Pragma("unroll")                                           \
        for (int t = 0; t < NT; ++t) {                              \
            *(f32x4*)&lds[r][0][t][lane][0] = aU[t];                \
            *(f32x4*)&lds[r][1][t][lane][0] = aV[t];                \
        }                                                           \
    } while (0)
#define ADD_FRAGS(r)                                                \
    do {                                                            \
        _Pragma("unroll")                                           \
        for (int t = 0; t < NT; ++t) {                              \
            aU[t] += *(const f32x4*)&lds[r][0][t][lane][0];         \
            aV[t] += *(const f32x4*)&lds[r][1][t][lane][0];         \
        }                                                           \
    } while (0)

    if (wave >= 4) STORE_FRAGS(wave - 4);
    __syncthreads();
    if (wave < 4) ADD_FRAGS(wave);
    __syncthreads();
    if (wave == 2 || wave == 3) STORE_FRAGS(wave - 2);
    __syncthreads();
    if (wave < 2) ADD_FRAGS(wave);
    __syncthreads();
    if (wave == 1) STORE_FRAGS(0);
    __syncthreads();

    if (wave == 0) {
        ADD_FRAGS(0);
        float du[4] = {0.f, 0.f, 0.f, 0.f};
        float dv[4] = {0.f, 0.f, 0.f, 0.f};
#pragma unroll
        for (int t = 0; t < NT; ++t) {
#pragma unroll
            for (int r = 0; r < 4; ++r) {
                du[r] += aU[t][r] * aU[t][r];
                dv[r] += aV[t][r] * aV[t][r];
            }
        }
#pragma unroll
        for (int msk = 1; msk < 16; msk <<= 1) {
#pragma unroll
            for (int r = 0; r < 4; ++r) {
                du[r] += __shfl_xor(du[r], msk, 64);
                dv[r] += __shfl_xor(dv[r], msk, 64);
            }
        }
        float s = 0.f;
#pragma unroll
        for (int r = 0; r < 4; ++r) {
            float l = du[r] - dv[r] + ALPHA;
            s += l > 0.f ? l : 0.f;
        }
        s += __shfl_xor(s, 16, 64);
        s += __shfl_xor(s, 32, 64);
        if (lane == 0) atomicAdd(out, s * (1.0f / BATCH));
    }
}

extern "C" void kernel_launch(void* const* d_in, const int* in_sizes, int n_in,
                              void* d_out, int out_size, void* d_ws, size_t ws_size,
                              hipStream_t stream) {
    const float* A  = (const float*)d_in[0];
    const float* P  = (const float*)d_in[1];
    const float* Ng = (const float*)d_in[2];
    const float* W  = (const float*)d_in[3];
    unsigned short* Wp = (unsigned short*)d_ws;   // 72*8*64*8 bf16 = 589,824 B

    hipMemsetAsync(d_out, 0, sizeof(float), stream);

    pack_w_kernel<<<(KDIM * EMBD) / 256, 256, 0, stream>>>(W, Wp);
    triplet_kernel<<<BATCH / 16, 512, 0, stream>>>(A, P, Ng, Wp, (float*)d_out);
}

// Round 4
// 234.472 us; speedup vs baseline: 1.0383x; 1.0084x over previous
//
#include <hip/hip_runtime.h>

// Triplet loss: mean(relu(|(a-p)W|^2 - |(a-n)W|^2 + 0.2)); bias cancels.
//
// R6 = R5's W-amortization lever at R4's PROVEN 96KB LDS footprint.
// (R5 @144KB LDS died at container level twice — likely infra flake, as
// R3 did too and its twin R4 then passed; but 144KB was the one new
// variable, so hedge it out.)
//
// Theory (from R5): R4 was vmem-THROUGHPUT-bound at ~9 B/cy/CU (521 MB
// total vmem: 226 MB A/P/N + 295 MB W reloads = 512 blocks x 576 KB).
// Each wave now owns TWO 16-row m-tiles (M=32/block): the same wf
// fragments feed both tiles' MFMAs, halving W traffic (147 MB, total
// 373 MB = 0.72x). NW=4 waves (256 thr), K-split 4 (18 chunks/wave),
// staging 2x12KB/wave -> LDS 96 KB; grid = 8192/32 = 256 blocks =
// exactly 1 block/CU, single round (R4 ran 2 rounds).
// Pipeline discipline unchanged: wave-private LDS double-buffer via
// global_load_lds (zero VGPRs held by in-flight data), counted
// s_waitcnt vmcnt(12) (stage(c+1)'s 12 ops are the only vmem guaranteed
// younger than stage(c) -> placement-independent, never drains the
// prefetch), no barriers in the main loop. In-flight/CU = 4x12KB = 48KB
// >> BW*latency ~10KB, so 4 waves keep the vmem pipe full.
//
// Layout (gfx950, mfma_f32_16x16x32_bf16):
//   A: lane holds A[m=lane&15][k=(lane>>4)*8+j]  (8 bf16)
//   B: lane holds B[k=(lane>>4)*8+j][n=lane&15]
//   C/D: lane holds D[row=(lane>>4)*4+reg][col=lane&15]

#define KDIM  2304   // 48*48
#define EMBD  128
#define BATCH 8192
#define NT    8      // 128 / 16 n-tiles
#define NW    4      // waves per block
#define MT    2      // 16-row m-tiles per wave (M=32/block)
#define CPW   18     // K-chunks (of 32) per wave: 72/4
#define ALPHA 0.2f

typedef __attribute__((ext_vector_type(8))) short short8;
typedef __attribute__((ext_vector_type(4))) float f32x4;
typedef __attribute__((ext_vector_type(4))) unsigned int u32x4;

#define AS1 __attribute__((address_space(1)))
#define AS3 __attribute__((address_space(3)))

__device__ __forceinline__ unsigned short f2bf(float f) {
    unsigned u = __builtin_bit_cast(unsigned, f);
    u += 0x7FFFu + ((u >> 16) & 1u);       // round-to-nearest-even
    return (unsigned short)(u >> 16);
}

// Coalesced-read pack: Wp[((c*8+t)*64+l)*8+j] = bf16(W[k][n]),
// k = c*32 + (l>>4)*8 + j, n = t*16 + (l&15).   (unchanged)
__global__ void pack_w_kernel(const float* __restrict__ W,
                              unsigned short* __restrict__ Wp) {
    int tid = blockIdx.x * blockDim.x + threadIdx.x;   // 0 .. 2304*128-1
    int n = tid & 127;
    int k = tid >> 7;
    int c = k >> 5;
    int q = (k >> 3) & 3;
    int j = k & 7;
    int t = n >> 4;
    int l = q * 16 + (n & 15);
    Wp[(size_t)(((c * 8 + t) * 64) + l) * 8 + j] = f2bf(W[tid]);
}

__device__ __forceinline__ unsigned cvtpk(float lo, float hi) {
    unsigned r;
    asm("v_cvt_pk_bf16_f32 %0, %1, %2" : "=v"(r) : "v"(lo), "v"(hi));
    return r;
}

// 16B/lane global->LDS DMA: LDS dest = uniform base + lane*16,
// global src is per-lane (pre-swizzled into fragment order).
__device__ __forceinline__ void gll16(const float* g, char* l) {
    __builtin_amdgcn_global_load_lds((AS1 void*)(void*)g, (AS3 void*)l, 16, 0, 0);
}

// 6 fragment reads (a_lo,a_hi,p_lo,p_hi,n_lo,n_hi) from one m-tile's
// half of this wave's buffer. lgkmcnt(0) inside the asm block =>
// outputs valid at block end (no rule-18 hoist hazard: MFMA consumes
// asm outputs). "memory" clobber pins ordering vs global_load_lds.
__device__ __forceinline__ void lds_read6(const char* p, f32x4& a0, f32x4& a1,
                                          f32x4& p0, f32x4& p1,
                                          f32x4& n0, f32x4& n1) {
    const AS3 char* lp = (const AS3 char*)p;
    asm volatile(
        "ds_read_b128 %0, %6 offset:0\n\t"
        "ds_read_b128 %1, %6 offset:1024\n\t"
        "ds_read_b128 %2, %6 offset:2048\n\t"
        "ds_read_b128 %3, %6 offset:3072\n\t"
        "ds_read_b128 %4, %6 offset:4096\n\t"
        "ds_read_b128 %5, %6 offset:5120\n\t"
        "s_waitcnt lgkmcnt(0)"
        : "=&v"(a0), "=&v"(a1), "=&v"(p0), "=&v"(p1), "=&v"(n0), "=&v"(n1)
        : "v"(lp)
        : "memory");
}

__global__ __launch_bounds__(256, 1) void triplet_kernel(
    const float* __restrict__ A, const float* __restrict__ P,
    const float* __restrict__ Ng, const unsigned short* __restrict__ Wp,
    float* __restrict__ out)
{
    // 4 waves x (2 bufs x 12KB) staging = 96KB; reduce tree aliased.
    __shared__ __align__(16) char smem[NW * 24576];

    const int lane = threadIdx.x & 63;
    const int wave = threadIdx.x >> 6;
    const int c0   = wave * CPW;             // this wave's first K-chunk

    // Per-lane global bases in fragment order, one per m-tile:
    // row = blk*32 + mt*16 + (lane&15), col = (lane>>4)*8 floats.
    const size_t goff0 = (size_t)(blockIdx.x * 32 + (lane & 15)) * KDIM
                       + (size_t)(lane >> 4) * 8 + (size_t)c0 * 32;
    const size_t goff1 = goff0 + (size_t)16 * KDIM;
    const float* gA0 = A  + goff0;  const float* gA1 = A  + goff1;
    const float* gP0 = P  + goff0;  const float* gP1 = P  + goff1;
    const float* gN0 = Ng + goff0;  const float* gN1 = Ng + goff1;

    char* wb = smem + wave * 24576;          // wave-private staging

    const short8* wp = (const short8*)Wp + lane + (size_t)c0 * NT * 64;

    f32x4 aU[MT][NT], aV[MT][NT];
#pragma unroll
    for (int mt = 0; mt < MT; ++mt)
#pragma unroll
        for (int t = 0; t < NT; ++t) {
            aU[mt][t] = (f32x4){0.f, 0.f, 0.f, 0.f};
            aV[mt][t] = (f32x4){0.f, 0.f, 0.f, 0.f};
        }

    // buf layout (12KB): mt0 {A@0,A@1024,P@2048,P@3072,N@4096,N@5120},
    //                    mt1 same +6144.
#define STAGE(cc, bufoff)                                   \
    do {                                                    \
        const int _o = (cc) * 32;                           \
        char* _b = wb + (bufoff);                           \
        gll16(gA0 + _o,     _b);                            \
        gll16(gA0 + _o + 4, _b + 1024);                     \
        gll16(gP0 + _o,     _b + 2048);                     \
        gll16(gP0 + _o + 4, _b + 3072);                     \
        gll16(gN0 + _o,     _b + 4096);                     \
        gll16(gN0 + _o + 4, _b + 5120);                     \
        gll16(gA1 + _o,     _b + 6144);                     \
        gll16(gA1 + _o + 4, _b + 7168);                     \
        gll16(gP1 + _o,     _b + 8192);                     \
        gll16(gP1 + _o + 4, _b + 9216);                     \
        gll16(gN1 + _o,     _b + 10240);                    \
        gll16(gN1 + _o + 4, _b + 11264);                    \
    } while (0)

    STAGE(0, 0);                             // prologue: chunk 0 -> buf0

#pragma unroll
    for (int c = 0; c < CPW; ++c) {
        // 1. W fragments for chunk c (coalesced 1KB each, L2-resident);
        //    reused by BOTH m-tiles (the amortization lever).
        short8 wf[NT];
#pragma unroll
        for (int t = 0; t < NT; ++t) wf[t] = wp[c * 512 + t * 64];

        // 2. prefetch chunk c+1, then counted wait: only stage(c+1)'s
        //    12 ops are guaranteed younger than stage(c) (asm memory
        //    fences pin order), so vmcnt(12) retires stage(c)
        //    regardless of scheduler placement, never drains prefetch.
        if (c + 1 < CPW) {
            STAGE(c + 1, ((c + 1) & 1) * 12288);
            asm volatile("s_waitcnt vmcnt(12)" ::: "memory");
        } else {
            asm volatile("s_waitcnt vmcnt(0)" ::: "memory");  // tail, once
        }

        // 3. per m-tile: fragment reads, pack, MFMA
#pragma unroll
        for (int mt = 0; mt < MT; ++mt) {
            const char* rp = wb + (c & 1) * 12288 + mt * 6144 + lane * 16;
            f32x4 xa0, xa1, xp0, xp1, xn0, xn1;
            lds_read6(rp, xa0, xa1, xp0, xp1, xn0, xn1);

            f32x4 ul = xa0 - xp0, uh = xa1 - xp1;
            f32x4 vl = xa0 - xn0, vh = xa1 - xn1;
            u32x4 uw, vw;
            uw[0] = cvtpk(ul[0], ul[1]); uw[1] = cvtpk(ul[2], ul[3]);
            uw[2] = cvtpk(uh[0], uh[1]); uw[3] = cvtpk(uh[2], uh[3]);
            vw[0] = cvtpk(vl[0], vl[1]); vw[1] = cvtpk(vl[2], vl[3]);
            vw[2] = cvtpk(vh[0], vh[1]); vw[3] = cvtpk(vh[2], vh[3]);
            short8 uf = __builtin_bit_cast(short8, uw);
            short8 vf = __builtin_bit_cast(short8, vw);

#pragma unroll
            for (int t = 0; t < NT; ++t) {
                aU[mt][t] = __builtin_amdgcn_mfma_f32_16x16x32_bf16(uf, wf[t], aU[mt][t], 0, 0, 0);
                aV[mt][t] = __builtin_amdgcn_mfma_f32_16x16x32_bf16(vf, wf[t], aV[mt][t], 0, 0, 0);
            }
        }
    }

    __syncthreads();

    // ---- cross-wave fragment reduce: 4 -> 2 -> 1 (wave 0 holds sum),
    //      aliased onto the staging LDS (2 regions x 32KB = 64KB) ----
    float (*lds)[MT][2][NT][64][4] = (float(*)[MT][2][NT][64][4])(void*)smem;

#define STORE_FRAGS(r)                                              \
    do {                                                            \
        _Pragma("unroll")                                           \
        for (int mt = 0; mt < MT; ++mt)                             \
        { _Pragma("unroll")                                         \
          for (int t = 0; t < NT; ++t) {                            \
            *(f32x4*)&lds[r][mt][0][t][lane][0] = aU[mt][t];        \
            *(f32x4*)&lds[r][mt][1][t][lane][0] = aV[mt][t];        \
          } }                                                       \
    } while (0)
#define ADD_FRAGS(r)                                                \
    do {                                                            \
        _Pragma("unroll")                                           \
        for (int mt = 0; mt < MT; ++mt)                             \
        { _Pragma("unroll")                                         \
          for (int t = 0; t < NT; ++t) {                            \
            aU[mt][t] += *(const f32x4*)&lds[r][mt][0][t][lane][0]; \
            aV[mt][t] += *(const f32x4*)&lds[r][mt][1][t][lane][0]; \
          } }                                                       \
    } while (0)

    if (wave >= 2) STORE_FRAGS(wave - 2);    // waves 2,3 -> regions 0,1
    __syncthreads();
    if (wave < 2) ADD_FRAGS(wave);
    __syncthreads();
    if (wave == 1) STORE_FRAGS(0);
    __syncthreads();

    if (wave == 0) {
        ADD_FRAGS(0);
        float du[MT][4], dv[MT][4];
#pragma unroll
        for (int mt = 0; mt < MT; ++mt)
#pragma unroll
            for (int r = 0; r < 4; ++r) { du[mt][r] = 0.f; dv[mt][r] = 0.f; }
#pragma unroll
        for (int mt = 0; mt < MT; ++mt)
#pragma unroll
            for (int t = 0; t < NT; ++t)
#pragma unroll
                for (int r = 0; r < 4; ++r) {
                    du[mt][r] += aU[mt][t][r] * aU[mt][t][r];
                    dv[mt][r] += aV[mt][t][r] * aV[mt][t][r];
                }
#pragma unroll
        for (int msk = 1; msk < 16; msk <<= 1)
#pragma unroll
            for (int mt = 0; mt < MT; ++mt)
#pragma unroll
                for (int r = 0; r < 4; ++r) {
                    du[mt][r] += __shfl_xor(du[mt][r], msk, 64);
                    dv[mt][r] += __shfl_xor(dv[mt][r], msk, 64);
                }
        float s = 0.f;
#pragma unroll
        for (int mt = 0; mt < MT; ++mt)
#pragma unroll
            for (int r = 0; r < 4; ++r) {
                float l = du[mt][r] - dv[mt][r] + ALPHA;
                s += l > 0.f ? l : 0.f;
            }
        s += __shfl_xor(s, 16, 64);
        s += __shfl_xor(s, 32, 64);
        if (lane == 0) atomicAdd(out, s * (1.0f / BATCH));
    }
}

extern "C" void kernel_launch(void* const* d_in, const int* in_sizes, int n_in,
                              void* d_out, int out_size, void* d_ws, size_t ws_size,
                              hipStream_t stream) {
    const float* A  = (const float*)d_in[0];
    const float* P  = (const float*)d_in[1];
    const float* Ng = (const float*)d_in[2];
    const float* W  = (const float*)d_in[3];
    unsigned short* Wp = (unsigned short*)d_ws;   // 72*8*64*8 bf16 = 589,824 B

    hipMemsetAsync(d_out, 0, sizeof(float), stream);

    pack_w_kernel<<<(KDIM * EMBD) / 256, 256, 0, stream>>>(W, Wp);
    triplet_kernel<<<BATCH / 32, 256, 0, stream>>>(A, P, Ng, Wp, (float*)d_out);
}